// Round 2
// baseline (9047.694 us; speedup 1.0000x reference)
//
#include <hip/hip_runtime.h>
#include <hip/hip_bf16.h>
#include <math.h>

#define Bq 64
#define Sq 300
#define NH 4
#define DHd 32
#define Dd 128
#define NL 8
#define FF 512
#define NIN 36

__device__ __forceinline__ float gelu_f(float x) {
    return 0.5f * x * (1.0f + erff(x * 0.70710678118654752f));
}
__device__ __forceinline__ bool bf16_mode(const unsigned* maskw) {
    return maskw[0] == 0x3F803F80u;   // two bf16 1.0s; f32 1.0 is 0x3F800000
}

// -------- dtype-agnostic input widening: all 36 inputs -> fp32 shadow in ws --------
struct ConvArgs {
    const void* src[NIN];
    float* dst[NIN];
    int n[NIN];
};

__global__ void convert_kernel(ConvArgs a, const unsigned* maskw) {
    bool bfm = bf16_mode(maskw);
    int bi = blockIdx.y;
    int n = a.n[bi];
    float* dst = a.dst[bi];
    int stride = gridDim.x * blockDim.x;
    int i0 = blockIdx.x * blockDim.x + threadIdx.x;
    if (bfm) {
        const __hip_bfloat16* s = (const __hip_bfloat16*)a.src[bi];
        for (int i = i0; i < n; i += stride) dst[i] = __bfloat162float(s[i]);
    } else {
        const float* s = (const float*)a.src[bi];
        for (int i = i0; i < n; i += stride) dst[i] = s[i];
    }
}

// -------- embedding: MLP(3->64->128->128) + tok_emb + LN + mask --------
__global__ void embed_kernel(const float* inp, const float* mask,
                             const float* W1, const float* b1,
                             const float* W2, const float* b2,
                             const float* W3, const float* b3,
                             const float* tok_emb,
                             const float* ln_s, const float* ln_b,
                             float* x) {
    int row = blockIdx.x;      // b*S+s
    int t = threadIdx.x;       // 0..127
    __shared__ float f[4];
    __shared__ float e1[64];
    __shared__ float e2[128];
    __shared__ float red[128];
    if (t < 4) f[t] = inp[row * 4 + t];
    __syncthreads();
    if (t < 64) {
        float a = b1[t];
        for (int k = 0; k < 3; k++) a += f[k] * W1[k * 64 + t];
        e1[t] = gelu_f(a);
    }
    __syncthreads();
    {
        float a = b2[t];
        for (int k = 0; k < 64; k++) a += e1[k] * W2[k * 128 + t];
        e2[t] = gelu_f(a);
    }
    __syncthreads();
    float a3 = b3[t];
    for (int k = 0; k < 128; k++) a3 += e2[k] * W3[k * 128 + t];
    a3 = gelu_f(a3);
    int tok = (int)f[3];
    a3 += tok_emb[tok * 128 + t];
    red[t] = a3; __syncthreads();
    for (int s = 64; s > 0; s >>= 1) { if (t < s) red[t] += red[t + s]; __syncthreads(); }
    float mu = red[0] * (1.0f / 128.0f); __syncthreads();
    float dv = a3 - mu;
    red[t] = dv * dv; __syncthreads();
    for (int s = 64; s > 0; s >>= 1) { if (t < s) red[t] += red[t + s]; __syncthreads(); }
    float var = red[0] * (1.0f / 128.0f);
    float y = dv * rsqrtf(var + 1e-7f) * ln_s[t] + ln_b[t];
    y *= mask[row];
    x[row * 128 + t] = y;
}

// -------- qkv projection: x[row,128] @ W[128,384]; scatter to q/k/v [B,H,S,DH] --------
__global__ void qkv_kernel(const float* x, const float* W,
                           const float* qb, const float* vb,
                           float* q, float* k, float* v) {
    int row = blockIdx.x;
    int t = threadIdx.x;   // 0..383
    __shared__ float xs[128];
    if (t < 128) xs[t] = x[row * 128 + t];
    __syncthreads();
    float a = 0.0f;
    for (int kk = 0; kk < 128; kk++) a += xs[kk] * W[kk * 384 + t];
    int h = t / 96, m = (t % 96) / 32, d = t % 32;
    int b = row / Sq, s = row % Sq;
    int idx = ((b * NH + h) * Sq + s) * 32 + d;
    const float inv_scale = 0.10206207261596576f;  // 1/sqrt(96)
    if (m == 0)      q[idx] = (a + qb[h * 32 + d]) * inv_scale;
    else if (m == 1) k[idx] = a;
    else             v[idx] = a + vb[h * 32 + d];
}

// -------- per-layer positional projections: posk/posq [16,128] --------
__global__ void pos_kernel(const float* rel_emb,
                           const float* pkW, const float* pqW, const float* pqb,
                           float* posk, float* posq) {
    int bi = blockIdx.x;        // 0..31
    int which = bi >> 4;        // 0: posk, 1: posq
    int r = bi & 15;
    int t = threadIdx.x;        // 0..127
    __shared__ float re[128];
    re[t] = rel_emb[r * 128 + t];
    __syncthreads();
    const float* W = which ? pqW : pkW;
    float a = 0.0f;
    for (int k = 0; k < 128; k++) a += re[k] * W[k * 128 + t];
    if (which) { a = (a + pqb[t]) * 0.10206207261596576f; posq[r * 128 + t] = a; }
    else       { posk[r * 128 + t] = a; }
}

// -------- c2p[b,h,s,16] = q . posk[h,r]; p2c[b,h,s,16] = k . posq[h,r] --------
__global__ void relscore_kernel(const float* q, const float* k,
                                const float* posk, const float* posq,
                                float* c2p, float* p2c) {
    int bh = blockIdx.x;       // 0..255
    int h = bh % NH;
    int t = threadIdx.x;       // 0..255
    __shared__ float pk[16 * 32];
    __shared__ float pq[16 * 32];
    for (int i = t; i < 512; i += 256) {
        int r = i / 32, d = i % 32;
        pk[i] = posk[r * 128 + h * 32 + d];
        pq[i] = posq[r * 128 + h * 32 + d];
    }
    __syncthreads();
    const float* qb = q + (size_t)bh * Sq * 32;
    const float* kb = k + (size_t)bh * Sq * 32;
    float* c2pb = c2p + (size_t)bh * Sq * 16;
    float* p2cb = p2c + (size_t)bh * Sq * 16;
    for (int idx = t; idx < 2 * Sq * 16; idx += 256) {
        int sel = idx / (Sq * 16);
        int rem = idx % (Sq * 16);
        int s = rem / 16, r = rem % 16;
        const float* src = sel ? (kb + s * 32) : (qb + s * 32);
        const float* pp  = sel ? (pq + r * 32) : (pk + r * 32);
        float a = 0.0f;
        for (int d = 0; d < 32; d++) a += src[d] * pp[d];
        if (sel) p2cb[s * 16 + r] = a; else c2pb[s * 16 + r] = a;
    }
}

// -------- fused attention row: scores + rel-bias + softmax + probs@V --------
__global__ __launch_bounds__(320) void attn_kernel(const float* q, const float* k, const float* v,
                                                   const float* c2p, const float* p2c,
                                                   const float* mask, float* ctx) {
    int gid = blockIdx.x;
    int qi = gid % Sq;
    int bh = gid / Sq;
    int b = bh / NH, h = bh % NH;
    int t = threadIdx.x;           // 0..319
    __shared__ float qs[32];
    __shared__ float cs[16];
    __shared__ float sc[Sq];
    __shared__ float red[320];
    if (t < 32) qs[t] = q[((size_t)bh * Sq + qi) * 32 + t];
    if (t >= 32 && t < 48) cs[t - 32] = c2p[((size_t)bh * Sq + qi) * 16 + (t - 32)];
    __syncthreads();
    float qm = mask[b * Sq + qi];
    float s_val = -3.0e38f;
    bool valid = false;
    if (t < Sq) {
        const float* kr = k + ((size_t)bh * Sq + t) * 32;
        float a = 0.0f;
        for (int d = 0; d < 32; d++) a += qs[d] * kr[d];
        int r = qi - t + 8; r = r < 0 ? 0 : (r > 15 ? 15 : r);
        a += cs[r] + p2c[((size_t)bh * Sq + t) * 16 + r];
        float km = mask[b * Sq + t];
        valid = (qm * km) > 0.0f;
        s_val = valid ? a : -3.0e38f;
    }
    red[t] = s_val; __syncthreads();
    for (int s = 256; s > 0; s >>= 1) {
        if (t < s && t + s < 320) red[t] = fmaxf(red[t], red[t + s]);
        __syncthreads();
    }
    float mx = red[0]; __syncthreads();
    float p = (t < Sq && valid) ? expf(s_val - mx) : 0.0f;
    red[t] = p; __syncthreads();
    for (int s = 256; s > 0; s >>= 1) {
        if (t < s && t + s < 320) red[t] += red[t + s];
        __syncthreads();
    }
    float sum = red[0];
    float inv = sum > 0.0f ? 1.0f / sum : 0.0f;
    __syncthreads();
    if (t < Sq) sc[t] = p * inv;
    __syncthreads();
    if (t < 32) {
        float a = 0.0f;
        for (int j = 0; j < Sq; j++) a += sc[j] * v[((size_t)bh * Sq + j) * 32 + t];
        ctx[((size_t)(b * Sq + qi)) * 128 + h * 32 + t] = a;
    }
}

// -------- attn_out proj + residual + LN --------
__global__ void attnout_ln_kernel(const float* ctx, const float* W, const float* bias,
                                  const float* ln_s, const float* ln_b, float* x) {
    int row = blockIdx.x;
    int t = threadIdx.x;    // 0..127
    __shared__ float cs[128];
    __shared__ float red[128];
    cs[t] = ctx[row * 128 + t];
    __syncthreads();
    float a = bias[t] + x[row * 128 + t];
    for (int k = 0; k < 128; k++) a += cs[k] * W[k * 128 + t];
    red[t] = a; __syncthreads();
    for (int s = 64; s > 0; s >>= 1) { if (t < s) red[t] += red[t + s]; __syncthreads(); }
    float mu = red[0] * (1.0f / 128.0f); __syncthreads();
    float dv = a - mu;
    red[t] = dv * dv; __syncthreads();
    for (int s = 64; s > 0; s >>= 1) { if (t < s) red[t] += red[t + s]; __syncthreads(); }
    float var = red[0] * (1.0f / 128.0f);
    x[row * 128 + t] = dv * rsqrtf(var + 1e-7f) * ln_s[t] + ln_b[t];
}

// -------- fused FFN: gelu(x@W1+b1)@W2+b2 + residual + LN --------
__global__ __launch_bounds__(512) void ffn_kernel(const float* W1, const float* b1,
                                                  const float* W2, const float* b2,
                                                  const float* ln_s, const float* ln_b,
                                                  float* x) {
    int row = blockIdx.x;
    int t = threadIdx.x;    // 0..511
    __shared__ float xs[128];
    __shared__ float hs[512];
    __shared__ float red[128];
    if (t < 128) xs[t] = x[row * 128 + t];
    __syncthreads();
    {
        float a = b1[t];
        for (int k = 0; k < 128; k++) a += xs[k] * W1[k * 512 + t];
        hs[t] = gelu_f(a);
    }
    __syncthreads();
    float y = 0.0f;
    if (t < 128) {
        y = b2[t] + xs[t];
        for (int k = 0; k < 512; k++) y += hs[k] * W2[k * 128 + t];
        red[t] = y;
    }
    __syncthreads();
    for (int s = 64; s > 0; s >>= 1) { if (t < s) red[t] += red[t + s]; __syncthreads(); }
    float mu = red[0] * (1.0f / 128.0f); __syncthreads();
    float dv = y - mu;
    if (t < 128) red[t] = dv * dv;
    __syncthreads();
    for (int s = 64; s > 0; s >>= 1) { if (t < s) red[t] += red[t + s]; __syncthreads(); }
    float var = red[0] * (1.0f / 128.0f);
    if (t < 128)
        x[row * 128 + t] = dv * rsqrtf(var + 1e-7f) * ln_s[t] + ln_b[t];
}

// -------- reconstruction MLP: 128->128->64->5 (all gelu) --------
__global__ void rec_kernel(const float* x,
                           const float* W1, const float* b1,
                           const float* W2, const float* b2,
                           const float* W3, const float* b3,
                           float* r3) {
    int row = blockIdx.x;
    int t = threadIdx.x;    // 0..127
    __shared__ float xs[128];
    __shared__ float r1[128];
    __shared__ float r2[64];
    xs[t] = x[row * 128 + t];
    __syncthreads();
    {
        float a = b1[t];
        for (int k = 0; k < 128; k++) a += xs[k] * W1[k * 128 + t];
        r1[t] = gelu_f(a);
    }
    __syncthreads();
    if (t < 64) {
        float a = b2[t];
        for (int k = 0; k < 128; k++) a += r1[k] * W2[k * 64 + t];
        r2[t] = gelu_f(a);
    }
    __syncthreads();
    if (t < 5) {
        float a = b3[t];
        for (int k = 0; k < 64; k++) a += r2[k] * W3[k * 5 + t];
        r3[row * 5 + t] = gelu_f(a);
    }
}

// -------- connection head: [64,1500] @ [1500,2500] + b; dual-dtype output --------
__global__ void conn_kernel(const float* r3, const float* W, const float* b,
                            void* out, const unsigned* maskw) {
    bool bfm = bf16_mode(maskw);
    int bb = blockIdx.x;                       // 0..63
    int col = blockIdx.y * 256 + threadIdx.x;  // 0..2499
    __shared__ float rs[1500];
    for (int i = threadIdx.x; i < 1500; i += 256) rs[i] = r3[bb * 1500 + i];
    __syncthreads();
    if (col < 2500) {
        float a = b[col];
        for (int k = 0; k < 1500; k++) a += rs[k] * W[k * 2500 + col];
        if (bfm) ((__hip_bfloat16*)out)[bb * 2500 + col] = __float2bfloat16(a);
        else     ((float*)out)[bb * 2500 + col] = a;
    }
}

extern "C" void kernel_launch(void* const* d_in, const int* in_sizes, int n_in,
                              void* d_out, int out_size, void* d_ws, size_t ws_size,
                              hipStream_t stream) {
    float* ws = (float*)d_ws;

    // fp32 shadow copies of all inputs at the head of ws
    float* cv[NIN];
    size_t off = 0;
    for (int i = 0; i < NIN; i++) { cv[i] = ws + off; off += (size_t)in_sizes[i]; }

    const float* inp      = cv[0];
    const float* mask     = cv[1];
    const float* emb_W1   = cv[2];
    const float* emb_b1   = cv[3];
    const float* emb_W2   = cv[4];
    const float* emb_b2   = cv[5];
    const float* emb_W3   = cv[6];
    const float* emb_b3   = cv[7];
    const float* tok_emb  = cv[8];
    const float* emb_ln_s = cv[9];
    const float* emb_ln_b = cv[10];
    const float* rel_emb  = cv[11];
    const float* qkv_W    = cv[12];
    const float* q_bias   = cv[13];
    const float* v_bias   = cv[14];
    const float* pos_k_W  = cv[15];
    const float* pos_q_W  = cv[16];
    const float* pos_q_b  = cv[17];
    const float* attn_out_W = cv[18];
    const float* attn_out_b = cv[19];
    const float* ln1_s    = cv[20];
    const float* ln1_b    = cv[21];
    const float* ffn_W1   = cv[22];
    const float* ffn_b1   = cv[23];
    const float* ffn_W2   = cv[24];
    const float* ffn_b2   = cv[25];
    const float* ln2_s    = cv[26];
    const float* ln2_b    = cv[27];
    const float* rec_W1   = cv[28];
    const float* rec_b1   = cv[29];
    const float* rec_W2   = cv[30];
    const float* rec_b2   = cv[31];
    const float* rec_W3   = cv[32];
    const float* rec_b3   = cv[33];
    const float* conn_W   = cv[34];
    const float* conn_b   = cv[35];

    const int NTOK = Bq * Sq;            // 19200
    float* x    = ws + off;              // 19200*128
    float* q    = x    + (size_t)NTOK * 128;
    float* k    = q    + (size_t)Bq * NH * Sq * 32;
    float* v    = k    + (size_t)Bq * NH * Sq * 32;
    float* ctx  = v    + (size_t)Bq * NH * Sq * 32;
    float* c2p  = ctx  + (size_t)NTOK * 128;
    float* p2c  = c2p  + (size_t)Bq * NH * Sq * 16;
    float* posk = p2c  + (size_t)Bq * NH * Sq * 16;
    float* posq = posk + 16 * 128;
    float* r3b  = posq + 16 * 128;       // 19200*5

    const unsigned* maskw = (const unsigned*)d_in[1];

    ConvArgs ca;
    for (int i = 0; i < NIN; i++) {
        ca.src[i] = d_in[i];
        ca.dst[i] = cv[i];
        ca.n[i] = in_sizes[i];
    }
    convert_kernel<<<dim3(256, NIN), 256, 0, stream>>>(ca, maskw);

    embed_kernel<<<NTOK, 128, 0, stream>>>(inp, mask, emb_W1, emb_b1, emb_W2, emb_b2,
                                           emb_W3, emb_b3, tok_emb, emb_ln_s, emb_ln_b, x);

    for (int l = 0; l < NL; l++) {
        qkv_kernel<<<NTOK, 384, 0, stream>>>(x, qkv_W + (size_t)l * 128 * 384,
                                             q_bias + l * 128, v_bias + l * 128, q, k, v);
        pos_kernel<<<32, 128, 0, stream>>>(rel_emb, pos_k_W + (size_t)l * 128 * 128,
                                           pos_q_W + (size_t)l * 128 * 128,
                                           pos_q_b + l * 128, posk, posq);
        relscore_kernel<<<Bq * NH, 256, 0, stream>>>(q, k, posk, posq, c2p, p2c);
        attn_kernel<<<Bq * NH * Sq, 320, 0, stream>>>(q, k, v, c2p, p2c, mask, ctx);
        attnout_ln_kernel<<<NTOK, 128, 0, stream>>>(ctx, attn_out_W + (size_t)l * 128 * 128,
                                                    attn_out_b + l * 128,
                                                    ln1_s + l * 128, ln1_b + l * 128, x);
        ffn_kernel<<<NTOK, 512, 0, stream>>>(ffn_W1 + (size_t)l * 128 * 512, ffn_b1 + l * 512,
                                             ffn_W2 + (size_t)l * 512 * 128, ffn_b2 + l * 128,
                                             ln2_s + l * 128, ln2_b + l * 128, x);
    }

    rec_kernel<<<NTOK, 128, 0, stream>>>(x, rec_W1, rec_b1, rec_W2, rec_b2, rec_W3, rec_b3, r3b);
    conn_kernel<<<dim3(Bq, 10), 256, 0, stream>>>(r3b, conn_W, conn_b, d_out, maskw);
}